// Round 1
// baseline (112.325 us; speedup 1.0000x reference)
//
#include <hip/hip_runtime.h>
#include <math.h>

#define NG 512
#define HW 512
#define NPIX (HW * HW)
#define TWO_PI 6.28318530717958647692f
#define TWO_PI_SQ 19.739208802178716f

// Per-gabor packed params in LDS (16 floats, 64 B, b128-aligned):
// [0]=uc [1]=vc [2]=cos(th) [3]=sin(th)
// [4]=-1/(2*sigma^2) [5]=-1/(2*gam^2) [6]=freq_rev=exp(-rel_freq) [7]=pad
// [8]=amp0*cosP0 [9]=amp0*sinP0 [10]=amp1*cosP1 [11]=amp1*sinP1
// [12]=amp2*cosP2 [13]=amp2*sinP2 [14]=pad [15]=pad

__global__ __launch_bounds__(256) void gabor_main(
    const float* __restrict__ gx, const float* __restrict__ gy,
    const float* __restrict__ u, const float* __restrict__ v,
    const float* __restrict__ theta, const float* __restrict__ rel_sigma,
    const float* __restrict__ rel_freq, const float* __restrict__ gamma_,
    const float* __restrict__ psi, const float* __restrict__ amplitude,
    float* __restrict__ out)
{
    __shared__ float sp[NG][16];

    // ---- per-block param setup (512 gabors / 256 threads = 2 each) ----
    for (int g = threadIdx.x; g < NG; g += 256) {
        float uc = fminf(fmaxf(u[g], -1.f), 1.f);
        float vc = fminf(fmaxf(v[g], -1.f), 1.f);
        float th = fminf(fmaxf(theta[g], 0.f), 1.f) * TWO_PI;
        float ct = cosf(th);
        float st = sinf(th);
        float zs = fminf(fmaxf(rel_sigma[g], -5.f), 5.f);
        float sig = 0.5f + 0.5f * tanhf(zs);
        float zg = fminf(fmaxf(gamma_[g], -5.f), 5.f);
        float gm = 0.001f + 0.5f * (1.f / (1.f + expf(-zg)));
        float nA = -1.f / (2.f * sig * sig);
        float nB = -1.f / (2.f * gm * gm);
        float frev = expf(-rel_freq[g]);   // freq/(2*pi)

        sp[g][0] = uc; sp[g][1] = vc; sp[g][2] = ct; sp[g][3] = st;
        sp[g][4] = nA; sp[g][5] = nB; sp[g][6] = frev; sp[g][7] = 0.f;
        #pragma unroll
        for (int c = 0; c < 3; ++c) {
            float a = fminf(fmaxf(amplitude[g * 3 + c], -5.f), 5.f);
            float amp = 0.2f * tanhf(a);
            float prad = psi[g * 3 + c] * TWO_PI_SQ;   // phase*pi in radians
            sp[g][8 + 2 * c]  = amp * cosf(prad);
            sp[g][9 + 2 * c]  = amp * sinf(prad);
        }
        sp[g][14] = 0.f; sp[g][15] = 0.f;
    }
    __syncthreads();

    // ---- per-pixel main loop ----
    const int pix = blockIdx.x * 256 + threadIdx.x;
    const float x = gx[pix];
    const float y = gy[pix];

    float a0 = 0.f, a1 = 0.f, a2 = 0.f;

    #pragma unroll 2
    for (int g = 0; g < NG; ++g) {
        const float4* p4 = reinterpret_cast<const float4*>(&sp[g][0]);
        float4 q0 = p4[0];   // uc, vc, ct, st
        float4 q1 = p4[1];   // nA, nB, frev, pad
        float4 q2 = p4[2];   // acp0, asp0, acp1, asp1
        float4 q3 = p4[3];   // acp2, asp2, pad, pad

        float dx = x - q0.x;
        float dy = y - q0.y;
        float xr = fmaf(dx, q0.z, dy * q0.w);        // dx*ct + dy*st
        float yr = fmaf(dx, q0.w, -dy * q0.z);       // dx*st - dy*ct (sign-free: squared)
        float e  = fmaf(xr * xr, q1.x, (yr * yr) * q1.y);
        e = fmaxf(e, -80.f);
        float gs = __expf(e);

        float b  = q1.z * xr;                        // revolutions
        float rb = b - floorf(b);                    // fract -> [0,1), hw domain
        float sb = __builtin_amdgcn_sinf(rb);        // sin(2*pi*rb)
        float cb = __builtin_amdgcn_cosf(rb);        // cos(2*pi*rb)

        // cos(B+P)*amp = cb*(amp cosP) - sb*(amp sinP)
        float t0 = fmaf(cb, q2.x, -sb * q2.y);
        float t1 = fmaf(cb, q2.z, -sb * q2.w);
        float t2 = fmaf(cb, q3.x, -sb * q3.y);
        a0 = fmaf(gs, t0, a0);
        a1 = fmaf(gs, t1, a1);
        a2 = fmaf(gs, t2, a2);
    }

    a0 = fminf(fmaxf(a0, -1.f), 1.f);
    a1 = fminf(fmaxf(a1, -1.f), 1.f);
    a2 = fminf(fmaxf(a2, -1.f), 1.f);

    out[pix]            = a0;
    out[NPIX + pix]     = a1;
    out[2 * NPIX + pix] = a2;
}

extern "C" void kernel_launch(void* const* d_in, const int* in_sizes, int n_in,
                              void* d_out, int out_size, void* d_ws, size_t ws_size,
                              hipStream_t stream) {
    const float* gx  = (const float*)d_in[0];
    const float* gy  = (const float*)d_in[1];
    const float* u   = (const float*)d_in[2];
    const float* v   = (const float*)d_in[3];
    const float* th  = (const float*)d_in[4];
    const float* rs  = (const float*)d_in[5];
    const float* rf  = (const float*)d_in[6];
    const float* gm  = (const float*)d_in[7];
    const float* psi = (const float*)d_in[8];
    const float* amp = (const float*)d_in[9];
    float* out = (float*)d_out;

    gabor_main<<<NPIX / 256, 256, 0, stream>>>(gx, gy, u, v, th, rs, rf, gm, psi, amp, out);
}